// Round 3
// baseline (3323.478 us; speedup 1.0000x reference)
//
#include <hip/hip_runtime.h>
#include <cstdint>
#include <cstddef>

#define H    500
#define G3   1500
#define SEQ  512
#define V    50000
#define NT   391          // ceil(50000/128)

#define NB   25           // GRU workgroups; HSL = 20 h-elements per WG
#define HSL  20
#define ROWS 60           // 3 gates x 20 rows per WG
#define NBLK 256          // total fused blocks: 25 GRU + 231 workers (1 per CU)

#define NGI  192          // gi_dec tiles: 24 n-tiles x 8 m-tiles of 64x64
#define TPB  (NT + 1)     // tickets per epoch: 1 ltgt + NT logits
#define NTICK (NGI + 4 * TPB)

// ---------------- workspace layout (bytes) ----------------
static constexpr size_t OFS_HBUF   = 0;            // [2 bufs][25 slices][32 u64]
static constexpr size_t OFS_CTRL   = 32768;        // ints: [0]=ticket [1]=gi_done [2..5]=epoch
static constexpr size_t OFS_GI_ENC = 65536;        // 512*1500 f32
static constexpr size_t OFS_GI_DEC = OFS_GI_ENC + 3276800;
static constexpr size_t OFS_DECHS  = OFS_GI_DEC + 3276800;   // 512*500 f32
static constexpr size_t OFS_SPART  = OFS_DECHS + 1048576;    // 512*NT f32
static constexpr size_t OFS_PPART  = OFS_SPART + 1048576;    // 512*NT u64
static constexpr size_t OFS_LTGT   = OFS_PPART + 2097152;    // 512 f32
static constexpr size_t OFS_SFIN   = OFS_LTGT + 4096;        // 512 f32

// ---------------- init: zero exchange buffers + control ----------------
__global__ __launch_bounds__(256) void k_init(unsigned long long* hbuf, int* ctrl)
{
    const int tid = threadIdx.x;
    for (int i = tid; i < 1600; i += 256) hbuf[i] = 0ull;
    if (tid < 8) ctrl[tid] = 0;
}

// ---------------- encoder input-gate GEMM: Gi = gather(emb)@Wih.T + bih ----------------
#define GI_BM 64
#define GI_BN 64
#define GI_BK 20
__global__ __launch_bounds__(256) void k_gi_enc(
    const float* __restrict__ emb, const float* __restrict__ Wih,
    const float* __restrict__ bih, const int* __restrict__ toks,
    float* __restrict__ Gi)
{
    __shared__ __align__(16) float As[GI_BK * GI_BM];
    __shared__ __align__(16) float Bs[GI_BK * GI_BN];
    const int tid = threadIdx.x;
    const int n0 = blockIdx.x * GI_BN;
    const int m0 = blockIdx.y * GI_BM;
    const int tx = tid & 15, ty = tid >> 4;
    float acc[4][4] = {};
    for (int k0 = 0; k0 < H; k0 += GI_BK) {
        for (int x = tid; x < 320; x += 256) {        // 64 rows x 5 float4
            int m = x / 5, kq = x - m * 5;
            int tok = toks[m0 + m];
            float4 v = *(const float4*)(emb + (size_t)tok * H + k0 + kq * 4);
            int kb = kq * 4;
            As[(kb + 0) * GI_BM + m] = v.x; As[(kb + 1) * GI_BM + m] = v.y;
            As[(kb + 2) * GI_BM + m] = v.z; As[(kb + 3) * GI_BM + m] = v.w;
        }
        for (int x = tid; x < 320; x += 256) {
            int n = x / 5, kq = x - n * 5;
            int gn = n0 + n;
            float4 v = make_float4(0.f, 0.f, 0.f, 0.f);
            if (gn < G3) v = *(const float4*)(Wih + (size_t)gn * H + k0 + kq * 4);
            int kb = kq * 4;
            Bs[(kb + 0) * GI_BN + n] = v.x; Bs[(kb + 1) * GI_BN + n] = v.y;
            Bs[(kb + 2) * GI_BN + n] = v.z; Bs[(kb + 3) * GI_BN + n] = v.w;
        }
        __syncthreads();
#pragma unroll 5
        for (int kk = 0; kk < GI_BK; ++kk) {
            float a[4], b[4];
            *(float4*)&a[0] = *(const float4*)&As[kk * GI_BM + ty * 4];
            *(float4*)&b[0] = *(const float4*)&Bs[kk * GI_BN + tx * 4];
#pragma unroll
            for (int i = 0; i < 4; i++)
#pragma unroll
                for (int j = 0; j < 4; j++) acc[i][j] = fmaf(a[i], b[j], acc[i][j]);
        }
        __syncthreads();
    }
#pragma unroll
    for (int i = 0; i < 4; i++) {
        int gm = m0 + ty * 4 + i;
#pragma unroll
        for (int j = 0; j < 4; j++) {
            int gn = n0 + tx * 4 + j;
            if (gn < G3) Gi[(size_t)gm * G3 + gn] = acc[i][j] + bih[gn];
        }
    }
}

// ---------------- fused: enc GRU -> dec GRU producers + persistent workers ----------------
// Blocks 0..24: GRU (enc phase t=0..511 then dec phase t=512..1023, h carried in regs).
// Blocks 25..255: workers. Phase A: gi_dec tiles (during enc). Phase B: per-epoch
// ltgt + 128x128 logits tiles, gated on epoch counters (RELEASE add / ACQUIRE poll).
#define LG_BM 128
#define LG_BN 128
#define LG_BK 20
__global__ __launch_bounds__(256, 1) void k_fused(
    const float* __restrict__ eWhh, const float* __restrict__ ebhh,
    const float* __restrict__ GiE,
    const float* __restrict__ dWhh, const float* __restrict__ dbhh,
    float* __restrict__ GiD,
    const float* __restrict__ demb, const float* __restrict__ dWih,
    const float* __restrict__ dbih, const int* __restrict__ tgt,
    const float* __restrict__ h0, unsigned long long* hbuf, int* ctrl,
    float* __restrict__ ench_out, float* __restrict__ dechs,
    const float* __restrict__ outW, const float* __restrict__ outb,
    float* __restrict__ ltgt,
    float* __restrict__ S_part, unsigned long long* __restrict__ P_part)
{
    __shared__ __align__(16) float As[LG_BK * LG_BM];   // worker staging (also gi tiles)
    __shared__ __align__(16) float Bs[LG_BK * LG_BN];
    __shared__ __align__(16) float h_s[H];
    __shared__ float p_s[ROWS * 26];
    __shared__ float gh_s[ROWS];
    __shared__ int go_s;
    const int tid = threadIdx.x;
    int* ticket  = ctrl + 0;
    int* gi_done = ctrl + 1;
    int* epoch   = ctrl + 2;

    if (blockIdx.x < NB) {
        // ================= GRU producer =================
        __builtin_amdgcn_s_setprio(2);
        const int wg = blockIdx.x;
        const int j0 = wg * HSL;
        const int g = tid / 25;
        const int s = tid - g * 25;
        const int slc = tid / 10;
        const int e0  = 2 * (tid - slc * 10);

        float wreg[6][20];
        if (tid < 250) {
#pragma unroll
            for (int r = 0; r < 6; ++r) {
                const int rl = g * 6 + r;
                const int gate = rl / 20, jl = rl - gate * 20;
                const float* wr = eWhh + (size_t)(gate * 500 + j0 + jl) * H + s * 20;
#pragma unroll
                for (int c = 0; c < 5; ++c)
                    *(float4*)&wreg[r][c * 4] = *(const float4*)(wr + c * 4);
            }
        }
        float bb = 0.f;
        if (tid < ROWS) {
            const int gate = tid / 20, jl = tid - gate * 20;
            bb = ebhh[gate * 500 + j0 + jl];
        }
        float hown = (tid < HSL) ? h0[j0 + tid] : 0.f;

        if (tid < HSL)
            __hip_atomic_store(hbuf + 800 + wg * 32 + tid,
                               ((unsigned long long)1u << 32) | (unsigned)__float_as_uint(hown),
                               __ATOMIC_RELAXED, __HIP_MEMORY_SCOPE_AGENT);

        for (int t = 0; t < 2 * SEQ; ++t) {
            if (t == SEQ) {
                // gate on gi_dec completion, then switch to decoder weights
                if (tid == 0) {
                    while (__hip_atomic_load(gi_done, __ATOMIC_ACQUIRE,
                                             __HIP_MEMORY_SCOPE_AGENT) < NGI)
                        __builtin_amdgcn_s_sleep(8);
                }
                __syncthreads();
                if (tid < 250) {
#pragma unroll
                    for (int r = 0; r < 6; ++r) {
                        const int rl = g * 6 + r;
                        const int gate = rl / 20, jl = rl - gate * 20;
                        const float* wr = dWhh + (size_t)(gate * 500 + j0 + jl) * H + s * 20;
#pragma unroll
                        for (int c = 0; c < 5; ++c)
                            *(float4*)&wreg[r][c * 4] = *(const float4*)(wr + c * 4);
                    }
                }
                if (tid < ROWS) {
                    const int gate = tid / 20, jl = tid - gate * 20;
                    bb = dbhh[gate * 500 + j0 + jl];
                }
            }
            const unsigned want = (unsigned)(t + 1);
            const int rb = (t + 1) & 1;
            float ir = 0.f, iz = 0.f, inn = 0.f;
            if (tid < HSL) {
                const float* gi = (t < SEQ ? GiE + (size_t)t * G3
                                           : GiD + (size_t)(t - SEQ) * G3) + j0 + tid;
                ir = gi[0]; iz = gi[500]; inn = gi[1000];
            }
            if (tid < 250) {
                const unsigned long long* pa = hbuf + rb * 800 + slc * 32 + e0;
                unsigned long long v0, v1;
                do {
                    v0 = __hip_atomic_load(pa,     __ATOMIC_RELAXED, __HIP_MEMORY_SCOPE_AGENT);
                    v1 = __hip_atomic_load(pa + 1, __ATOMIC_RELAXED, __HIP_MEMORY_SCOPE_AGENT);
                } while (((unsigned)(v0 >> 32) != want) || ((unsigned)(v1 >> 32) != want));
                h_s[2 * tid]     = __uint_as_float((unsigned)v0);
                h_s[2 * tid + 1] = __uint_as_float((unsigned)v1);
            }
            __syncthreads();
            if (tid < 250) {
                float hv[20];
#pragma unroll
                for (int c = 0; c < 5; ++c)
                    *(float4*)&hv[c * 4] = *(const float4*)&h_s[s * 20 + c * 4];
                float acc[6] = {0.f, 0.f, 0.f, 0.f, 0.f, 0.f};
#pragma unroll
                for (int i = 0; i < 20; ++i)
#pragma unroll
                    for (int r = 0; r < 6; ++r) acc[r] = fmaf(wreg[r][i], hv[i], acc[r]);
#pragma unroll
                for (int r = 0; r < 6; ++r) p_s[(g * 6 + r) * 26 + s] = acc[r];
            }
            __syncthreads();
            if (tid < ROWS) {
                float sum = 0.f;
#pragma unroll 5
                for (int i = 0; i < 25; ++i) sum += p_s[tid * 26 + i];
                gh_s[tid] = sum + bb;
            }
            __syncthreads();
            if (tid < HSL) {
                const int j = j0 + tid;
                const float hr = gh_s[tid], hz = gh_s[HSL + tid], hn = gh_s[2 * HSL + tid];
                const float r = 1.f / (1.f + __expf(-(ir + hr)));
                const float z = 1.f / (1.f + __expf(-(iz + hz)));
                const float n = tanhf(inn + r * hn);
                const float hnew = (1.f - z) * n + z * hown;
                hown = hnew;
                __hip_atomic_store(hbuf + (t & 1) * 800 + wg * 32 + tid,
                                   ((unsigned long long)(unsigned)(t + 2) << 32) |
                                   (unsigned)__float_as_uint(hnew),
                                   __ATOMIC_RELAXED, __HIP_MEMORY_SCOPE_AGENT);
                if (t == SEQ - 1) ench_out[j] = hnew;
                if (t >= SEQ)
                    __hip_atomic_store(&dechs[(size_t)(t - SEQ) * H + j], hnew,
                                       __ATOMIC_RELAXED, __HIP_MEMORY_SCOPE_AGENT);
            }
            if (t >= SEQ && ((t - SEQ) & 127) == 127) {
                __syncthreads();   // drains dechs stores (vmcnt(0) before barrier)
                if (tid == 0)
                    __hip_atomic_fetch_add(&epoch[(t - SEQ) >> 7], 1,
                                           __ATOMIC_RELEASE, __HIP_MEMORY_SCOPE_AGENT);
            }
        }
        return;
    }

    // ================= persistent worker =================
    int epoch_seen = -1;
    for (;;) {
        __syncthreads();
        if (tid == 0) go_s = atomicAdd(ticket, 1);
        __syncthreads();
        const int tk = go_s;
        if (tk >= NTICK) return;

        if (tk < NGI) {
            // ---- phase A: gi_dec 64x64 tile (runs during encoder phase) ----
            const int n0 = (tk % 24) * GI_BN;
            const int m0 = (tk / 24) * GI_BM;
            const int tx = tid & 15, ty = tid >> 4;
            float acc[4][4] = {};
            for (int k0 = 0; k0 < H; k0 += GI_BK) {
                for (int x = tid; x < 320; x += 256) {
                    int m = x / 5, kq = x - m * 5;
                    int gm = m0 + m;
                    int tok = (gm == 0) ? 0 : tgt[gm - 1];
                    float4 v = *(const float4*)(demb + (size_t)tok * H + k0 + kq * 4);
                    v.x = fmaxf(v.x, 0.f); v.y = fmaxf(v.y, 0.f);
                    v.z = fmaxf(v.z, 0.f); v.w = fmaxf(v.w, 0.f);
                    int kb = kq * 4;
                    As[(kb + 0) * GI_BM + m] = v.x; As[(kb + 1) * GI_BM + m] = v.y;
                    As[(kb + 2) * GI_BM + m] = v.z; As[(kb + 3) * GI_BM + m] = v.w;
                }
                for (int x = tid; x < 320; x += 256) {
                    int n = x / 5, kq = x - n * 5;
                    int gn = n0 + n;
                    float4 v = make_float4(0.f, 0.f, 0.f, 0.f);
                    if (gn < G3) v = *(const float4*)(dWih + (size_t)gn * H + k0 + kq * 4);
                    int kb = kq * 4;
                    Bs[(kb + 0) * GI_BM + n] = v.x; Bs[(kb + 1) * GI_BM + n] = v.y;
                    Bs[(kb + 2) * GI_BM + n] = v.z; Bs[(kb + 3) * GI_BM + n] = v.w;
                }
                __syncthreads();
#pragma unroll 5
                for (int kk = 0; kk < GI_BK; ++kk) {
                    float a[4], b[4];
                    *(float4*)&a[0] = *(const float4*)&As[kk * GI_BM + ty * 4];
                    *(float4*)&b[0] = *(const float4*)&Bs[kk * GI_BM + tx * 4];
#pragma unroll
                    for (int i = 0; i < 4; i++)
#pragma unroll
                        for (int j = 0; j < 4; j++) acc[i][j] = fmaf(a[i], b[j], acc[i][j]);
                }
                __syncthreads();
            }
#pragma unroll
            for (int i = 0; i < 4; i++) {
                int gm = m0 + ty * 4 + i;
#pragma unroll
                for (int j = 0; j < 4; j++) {
                    int gn = n0 + tx * 4 + j;
                    if (gn < G3)
                        __hip_atomic_store(&GiD[(size_t)gm * G3 + gn], acc[i][j] + dbih[gn],
                                           __ATOMIC_RELAXED, __HIP_MEMORY_SCOPE_AGENT);
                }
            }
            __syncthreads();   // drain gi stores
            if (tid == 0)
                __hip_atomic_fetch_add(gi_done, 1, __ATOMIC_RELEASE, __HIP_MEMORY_SCOPE_AGENT);
            continue;
        }

        // ---- phase B: epoch-gated ltgt / logits ----
        const int tk2 = tk - NGI;
        const int e = tk2 / TPB;
        const int r = tk2 - e * TPB;
        if (e > epoch_seen) {
            if (tid == 0) {
                while (__hip_atomic_load(&epoch[e], __ATOMIC_ACQUIRE,
                                         __HIP_MEMORY_SCOPE_AGENT) < NB)
                    __builtin_amdgcn_s_sleep(64);
            }
            __syncthreads();
            epoch_seen = e;
        }
        const int m0 = e * LG_BM;

        if (r == 0) {
            // ---- ltgt for rows [m0, m0+128) ----
            const int w = tid >> 6, lane = tid & 63;
            for (int rr = w; rr < LG_BM; rr += 4) {
                const int row = m0 + rr;
                const int tok = tgt[row];
                const float* a = dechs + (size_t)row * H;
                const float* b = outW + (size_t)tok * H;
                float sv = 0.f;
                for (int k = lane; k < H; k += 64) sv = fmaf(a[k], b[k], sv);
#pragma unroll
                for (int off = 1; off < 64; off <<= 1) sv += __shfl_xor(sv, off);
                if (lane == 0) ltgt[row] = sv + outb[tok];
            }
            continue;
        }

        // ---- logits 128x128 tile with fused sum-exp / argmax partials ----
        const int bx = r - 1;
        const int n0 = bx * LG_BN;
        const int tx = tid & 15, ty = tid >> 4;
        float acc[8][8] = {};
        for (int k0 = 0; k0 < H; k0 += LG_BK) {
            for (int x = tid; x < 640; x += 256) {      // 128 rows x 5 float4
                int m = x / 5, kq = x - m * 5;
                float4 v = *(const float4*)(dechs + (size_t)(m0 + m) * H + k0 + kq * 4);
                int kb = kq * 4;
                As[(kb + 0) * LG_BM + m] = v.x; As[(kb + 1) * LG_BM + m] = v.y;
                As[(kb + 2) * LG_BM + m] = v.z; As[(kb + 3) * LG_BM + m] = v.w;
            }
            for (int x = tid; x < 640; x += 256) {
                int n = x / 5, kq = x - n * 5;
                int gn = n0 + n;
                float4 v = make_float4(0.f, 0.f, 0.f, 0.f);
                if (gn < V) v = *(const float4*)(outW + (size_t)gn * H + k0 + kq * 4);
                int kb = kq * 4;
                Bs[(kb + 0) * LG_BN + n] = v.x; Bs[(kb + 1) * LG_BN + n] = v.y;
                Bs[(kb + 2) * LG_BN + n] = v.z; Bs[(kb + 3) * LG_BN + n] = v.w;
            }
            __syncthreads();
#pragma unroll 5
            for (int kk = 0; kk < LG_BK; ++kk) {
                float a[8], b[8];
                *(float4*)&a[0] = *(const float4*)&As[kk * LG_BM + ty * 8];
                *(float4*)&a[4] = *(const float4*)&As[kk * LG_BM + ty * 8 + 4];
                *(float4*)&b[0] = *(const float4*)&Bs[kk * LG_BN + tx * 8];
                *(float4*)&b[4] = *(const float4*)&Bs[kk * LG_BN + tx * 8 + 4];
#pragma unroll
                for (int i = 0; i < 8; i++)
#pragma unroll
                    for (int j = 0; j < 8; j++) acc[i][j] = fmaf(a[i], b[j], acc[i][j]);
            }
            __syncthreads();
        }
        float bcol[8]; int gncol[8]; bool bval[8];
#pragma unroll
        for (int j = 0; j < 8; j++) {
            int gn = n0 + tx * 8 + j;
            gncol[j] = gn; bval[j] = gn < V; bcol[j] = bval[j] ? outb[gn] : 0.f;
        }
#pragma unroll
        for (int i = 0; i < 8; i++) {
            int gm = m0 + ty * 8 + i;
            float mx = -3.4e38f; unsigned mi = 0; float se = 0.f;
#pragma unroll
            for (int j = 0; j < 8; j++) {
                if (bval[j]) {
                    float l = acc[i][j] + bcol[j];
                    se += __expf(l);
                    if (l > mx) { mx = l; mi = (unsigned)gncol[j]; }
                }
            }
            unsigned u = __float_as_uint(mx);
            unsigned key = (u & 0x80000000u) ? ~u : (u | 0x80000000u);
            unsigned long long pk = ((unsigned long long)key << 32) |
                                    (unsigned long long)(0xFFFFFFFFu - mi);
#pragma unroll
            for (int off = 1; off < 16; off <<= 1) {
                unsigned long long pk2 = __shfl_xor(pk, off);
                se += __shfl_xor(se, off);
                if (pk2 > pk) pk = pk2;
            }
            if (tx == 0) {
                S_part[(size_t)gm * NT + bx] = se;
                P_part[(size_t)gm * NT + bx] = pk;
            }
        }
    }
}

__global__ __launch_bounds__(128) void k_reduce_rows(
    const float* __restrict__ S_part, const unsigned long long* __restrict__ P_part,
    float* __restrict__ Sfin, float* __restrict__ out_argmax)
{
    const int row = blockIdx.x, tid = threadIdx.x;
    float s = 0.f; unsigned long long p = 0ull;
    for (int i = tid; i < NT; i += 128) {
        s += S_part[(size_t)row * NT + i];
        unsigned long long q = P_part[(size_t)row * NT + i];
        if (q > p) p = q;
    }
#pragma unroll
    for (int off = 1; off < 64; off <<= 1) {
        s += __shfl_xor(s, off);
        unsigned long long q = __shfl_xor(p, off);
        if (q > p) p = q;
    }
    __shared__ float s2[2];
    __shared__ unsigned long long p2[2];
    if ((tid & 63) == 0) { s2[tid >> 6] = s; p2[tid >> 6] = p; }
    __syncthreads();
    if (tid == 0) {
        s = s2[0] + s2[1];
        p = p2[0] > p2[1] ? p2[0] : p2[1];
        Sfin[row] = s;
        unsigned idx = 0xFFFFFFFFu - (unsigned)(p & 0xFFFFFFFFull);
        out_argmax[row] = (float)idx;
    }
}

__global__ __launch_bounds__(512) void k_final(
    const float* __restrict__ Sfin, const float* __restrict__ ltgt, float* __restrict__ d_out)
{
    __shared__ float red[512];
    const int t = threadIdx.x;
    red[t] = logf(Sfin[t]) - ltgt[t];
    __syncthreads();
    for (int s = 256; s > 0; s >>= 1) {
        if (t < s) red[t] += red[t + s];
        __syncthreads();
    }
    if (t == 0) d_out[0] = red[0];
}

extern "C" void kernel_launch(void* const* d_in, const int* in_sizes, int n_in,
                              void* d_out, int out_size, void* d_ws, size_t ws_size,
                              hipStream_t stream) {
    const int*   enc_ids = (const int*)d_in[0];
    const int*   tgt     = (const int*)d_in[1];
    const float* enc_h0  = (const float*)d_in[2];
    const float* enc_emb = (const float*)d_in[3];
    const float* enc_Wih = (const float*)d_in[4];
    const float* enc_Whh = (const float*)d_in[5];
    const float* enc_bih = (const float*)d_in[6];
    const float* enc_bhh = (const float*)d_in[7];
    const float* dec_emb = (const float*)d_in[8];
    const float* dec_Wih = (const float*)d_in[9];
    const float* dec_Whh = (const float*)d_in[10];
    const float* dec_bih = (const float*)d_in[11];
    const float* dec_bhh = (const float*)d_in[12];
    const float* out_W   = (const float*)d_in[13];
    const float* out_b   = (const float*)d_in[14];
    float* out = (float*)d_out;

    char* ws = (char*)d_ws;
    unsigned long long* hbuf = (unsigned long long*)(ws + OFS_HBUF);
    int*   ctrl   = (int*)(ws + OFS_CTRL);
    float* gi_enc = (float*)(ws + OFS_GI_ENC);
    float* gi_dec = (float*)(ws + OFS_GI_DEC);
    float* dechs  = (float*)(ws + OFS_DECHS);
    float* Spart  = (float*)(ws + OFS_SPART);
    unsigned long long* Ppart = (unsigned long long*)(ws + OFS_PPART);
    float* ltgt   = (float*)(ws + OFS_LTGT);
    float* Sfin   = (float*)(ws + OFS_SFIN);

    k_init<<<dim3(1), dim3(256), 0, stream>>>(hbuf, ctrl);
    k_gi_enc<<<dim3(24, 8), dim3(256), 0, stream>>>(enc_emb, enc_Wih, enc_bih,
                                                    enc_ids, gi_enc);
    k_fused<<<dim3(NBLK), dim3(256), 0, stream>>>(
        enc_Whh, enc_bhh, gi_enc,
        dec_Whh, dec_bhh, gi_dec,
        dec_emb, dec_Wih, dec_bih, tgt,
        enc_h0, hbuf, ctrl, out + 1, dechs,
        out_W, out_b, ltgt, Spart, Ppart);
    k_reduce_rows<<<dim3(SEQ), dim3(128), 0, stream>>>(Spart, Ppart, Sfin, out + 1 + H);
    k_final<<<dim3(1), dim3(512), 0, stream>>>(Sfin, ltgt, out);
}

// Round 4
// 2392.270 us; speedup vs baseline: 1.3893x; 1.3893x over previous
//
#include <hip/hip_runtime.h>
#include <cstdint>
#include <cstddef>

#define H    500
#define G3   1500
#define SEQ  512
#define V    50000
#define NT   391          // ceil(50000/128)
#define NTILES (NT * 4)

#define NB   25           // GRU workgroups; HSL = 20 h-elements per WG
#define HSL  20
#define ROWS 60           // 3 gates x 20 rows per WG
#define NWORK 231         // workers: NB+NWORK=256 -> 1 block/CU, GRU blocks own their CU

// ---------------- workspace layout (bytes) ----------------
static constexpr size_t OFS_HBUF_E = 0;            // [2 bufs][25 slices][32 u64]
static constexpr size_t OFS_HBUF_D = 16384;
static constexpr size_t OFS_ENCH   = 32768;        // 500 f32
static constexpr size_t OFS_TICKET = 49152;        // 1 int
static constexpr size_t OFS_GI_ENC = 65536;        // 512*1500 f32
static constexpr size_t OFS_GI_DEC = OFS_GI_ENC + 3276800;
static constexpr size_t OFS_DECHS  = OFS_GI_DEC + 3276800;   // 512*500 f32
static constexpr size_t OFS_SPART  = OFS_DECHS + 1048576;    // 512*NT f32
static constexpr size_t OFS_PPART  = OFS_SPART + 1048576;    // 512*NT u64
static constexpr size_t OFS_LTGT   = OFS_PPART + 2097152;    // 512 f32
static constexpr size_t OFS_SFIN   = OFS_LTGT + 4096;        // 512 f32

// ---------------- init: zero exchange buffers + ticket ----------------
__global__ __launch_bounds__(256) void k_init(unsigned long long* hbufE,
                                              unsigned long long* hbufD,
                                              int* ticket)
{
    const int tid = threadIdx.x;
    for (int i = tid; i < 1600; i += 256) { hbufE[i] = 0ull; hbufD[i] = 0ull; }
    if (tid == 0) *ticket = 0;
}

// ---------------- input-gate GEMM: Gi = gather(emb)@Wih.T + bih (enc z=0, dec z=1) ----------------
#define GI_BM 64
#define GI_BN 64
#define GI_BK 20
__global__ __launch_bounds__(256) void k_gi_gemm(
    const float* __restrict__ eA, const float* __restrict__ WA,
    const float* __restrict__ bA, const int* __restrict__ tA,
    const float* __restrict__ eB, const float* __restrict__ WB,
    const float* __restrict__ bB, const int* __restrict__ tB,
    float* __restrict__ GiA, float* __restrict__ GiB)
{
    const int dec = blockIdx.z;
    const float* emb = dec ? eB : eA;
    const float* Wih = dec ? WB : WA;
    const float* bih = dec ? bB : bA;
    const int*  toks = dec ? tB : tA;
    float* Gi        = dec ? GiB : GiA;

    __shared__ __align__(16) float As[GI_BK * GI_BM];
    __shared__ __align__(16) float Bs[GI_BK * GI_BN];
    const int tid = threadIdx.x;
    const int n0 = blockIdx.x * GI_BN;
    const int m0 = blockIdx.y * GI_BM;
    const int tx = tid & 15, ty = tid >> 4;
    float acc[4][4] = {};
    for (int k0 = 0; k0 < H; k0 += GI_BK) {
        for (int x = tid; x < 320; x += 256) {        // 64 rows x 5 float4
            int m = x / 5, kq = x - m * 5;
            int gm = m0 + m;
            int tok = dec ? ((gm == 0) ? 0 : toks[gm - 1]) : toks[gm];
            float4 v = *(const float4*)(emb + (size_t)tok * H + k0 + kq * 4);
            if (dec) { v.x = fmaxf(v.x, 0.f); v.y = fmaxf(v.y, 0.f);
                       v.z = fmaxf(v.z, 0.f); v.w = fmaxf(v.w, 0.f); }
            int kb = kq * 4;
            As[(kb + 0) * GI_BM + m] = v.x; As[(kb + 1) * GI_BM + m] = v.y;
            As[(kb + 2) * GI_BM + m] = v.z; As[(kb + 3) * GI_BM + m] = v.w;
        }
        for (int x = tid; x < 320; x += 256) {
            int n = x / 5, kq = x - n * 5;
            int gn = n0 + n;
            float4 v = make_float4(0.f, 0.f, 0.f, 0.f);
            if (gn < G3) v = *(const float4*)(Wih + (size_t)gn * H + k0 + kq * 4);
            int kb = kq * 4;
            Bs[(kb + 0) * GI_BN + n] = v.x; Bs[(kb + 1) * GI_BN + n] = v.y;
            Bs[(kb + 2) * GI_BN + n] = v.z; Bs[(kb + 3) * GI_BN + n] = v.w;
        }
        __syncthreads();
#pragma unroll 5
        for (int kk = 0; kk < GI_BK; ++kk) {
            float a[4], b[4];
            *(float4*)&a[0] = *(const float4*)&As[kk * GI_BM + ty * 4];
            *(float4*)&b[0] = *(const float4*)&Bs[kk * GI_BN + tx * 4];
#pragma unroll
            for (int i = 0; i < 4; i++)
#pragma unroll
                for (int j = 0; j < 4; j++) acc[i][j] = fmaf(a[i], b[j], acc[i][j]);
        }
        __syncthreads();
    }
#pragma unroll
    for (int i = 0; i < 4; i++) {
        int gm = m0 + ty * 4 + i;
#pragma unroll
        for (int j = 0; j < 4; j++) {
            int gn = n0 + tx * 4 + j;
            if (gn < G3) Gi[(size_t)gm * G3 + gn] = acc[i][j] + bih[gn];
        }
    }
}

// ---------------- persistent GRU scan (encoder): tagged-pair dataflow, r0-proven ----------------
__global__ __launch_bounds__(256, 1) void k_gru(
    const float* __restrict__ Whh, const float* __restrict__ bhh,
    const float* __restrict__ Gi, const float* __restrict__ h0,
    unsigned long long* hbuf, float* hfinal, float* douth, int S)
{
    __shared__ __align__(16) float h_s[H];
    __shared__ float p_s[ROWS * 26];   // partials, stride 26 breaks bank conflicts
    __shared__ float gh_s[ROWS];
    const int tid = threadIdx.x;
    const int wg = blockIdx.x;
    const int j0 = wg * HSL;

    const int g = tid / 25;            // 0..9  (tid<250)
    const int s = tid - g * 25;        // 0..24
    const int slc = tid / 10;
    const int e0  = 2 * (tid - slc * 10);

    float wreg[6][20];
    if (tid < 250) {
#pragma unroll
        for (int r = 0; r < 6; ++r) {
            const int rl = g * 6 + r;
            const int gate = rl / 20, jl = rl - gate * 20;
            const float* wr = Whh + (size_t)(gate * 500 + j0 + jl) * H + s * 20;
#pragma unroll
            for (int c = 0; c < 5; ++c)
                *(float4*)&wreg[r][c * 4] = *(const float4*)(wr + c * 4);
        }
    }
    float bb = 0.f;
    if (tid < ROWS) {
        const int gate = tid / 20, jl = tid - gate * 20;
        bb = bhh[gate * 500 + j0 + jl];
    }
    float hown = (tid < HSL) ? h0[j0 + tid] : 0.f;

    if (tid < HSL)
        __hip_atomic_store(hbuf + 800 + wg * 32 + tid,
                           ((unsigned long long)1u << 32) | (unsigned)__float_as_uint(hown),
                           __ATOMIC_RELAXED, __HIP_MEMORY_SCOPE_AGENT);

    for (int t = 0; t < S; ++t) {
        const unsigned want = (unsigned)(t + 1);
        const int rb = (t + 1) & 1;
        float ir = 0.f, iz = 0.f, inn = 0.f;
        if (tid < HSL) {
            const float* gi = Gi + (size_t)t * G3 + j0 + tid;
            ir = gi[0]; iz = gi[500]; inn = gi[1000];
        }
        if (tid < 250) {
            const unsigned long long* pa = hbuf + rb * 800 + slc * 32 + e0;
            unsigned long long v0, v1;
            do {
                v0 = __hip_atomic_load(pa,     __ATOMIC_RELAXED, __HIP_MEMORY_SCOPE_AGENT);
                v1 = __hip_atomic_load(pa + 1, __ATOMIC_RELAXED, __HIP_MEMORY_SCOPE_AGENT);
            } while (((unsigned)(v0 >> 32) != want) || ((unsigned)(v1 >> 32) != want));
            h_s[2 * tid]     = __uint_as_float((unsigned)v0);
            h_s[2 * tid + 1] = __uint_as_float((unsigned)v1);
        }
        __syncthreads();
        if (tid < 250) {
            float hv[20];
#pragma unroll
            for (int c = 0; c < 5; ++c)
                *(float4*)&hv[c * 4] = *(const float4*)&h_s[s * 20 + c * 4];
            float acc[6] = {0.f, 0.f, 0.f, 0.f, 0.f, 0.f};
#pragma unroll
            for (int i = 0; i < 20; ++i)
#pragma unroll
                for (int r = 0; r < 6; ++r) acc[r] = fmaf(wreg[r][i], hv[i], acc[r]);
#pragma unroll
            for (int r = 0; r < 6; ++r) p_s[(g * 6 + r) * 26 + s] = acc[r];
        }
        __syncthreads();
        if (tid < ROWS) {
            float sum = 0.f;
#pragma unroll 5
            for (int i = 0; i < 25; ++i) sum += p_s[tid * 26 + i];
            gh_s[tid] = sum + bb;
        }
        __syncthreads();
        if (tid < HSL) {
            const int j = j0 + tid;
            const float hr = gh_s[tid], hz = gh_s[HSL + tid], hn = gh_s[2 * HSL + tid];
            const float r = 1.f / (1.f + __expf(-(ir + hr)));
            const float z = 1.f / (1.f + __expf(-(iz + hz)));
            const float n = tanhf(inn + r * hn);
            const float hnew = (1.f - z) * n + z * hown;
            hown = hnew;
            __hip_atomic_store(hbuf + (t & 1) * 800 + wg * 32 + tid,
                               ((unsigned long long)(unsigned)(t + 2) << 32) |
                               (unsigned)__float_as_uint(hnew),
                               __ATOMIC_RELAXED, __HIP_MEMORY_SCOPE_AGENT);
            if (t == S - 1) {
                if (hfinal) hfinal[j] = hnew;
                if (douth)  douth[j]  = hnew;
            }
        }
    }
}

// ---------------- fused decoder: 25 GRU blocks + 231 persistent logits workers ----------------
#define LG_BM 128
#define LG_BN 128
#define LG_BK 20
__global__ __launch_bounds__(256, 1) void k_dec_fused(
    const float* __restrict__ Whh, const float* __restrict__ bhh,
    const float* __restrict__ Gi,  const float* __restrict__ h0,
    unsigned long long* hbuf, float* __restrict__ dechs,
    const float* __restrict__ outW, const float* __restrict__ outb,
    float* __restrict__ S_part, unsigned long long* __restrict__ P_part,
    int* ticket)
{
    const int tid = threadIdx.x;

    if (blockIdx.x < NB) {
        // ================= GRU producer (r0-proven structure) =================
        __builtin_amdgcn_s_setprio(2);
        __shared__ __align__(16) float h_s[H];
        __shared__ float p_s[ROWS * 26];
        __shared__ float gh_s[ROWS];
        const int wg = blockIdx.x;
        const int j0 = wg * HSL;
        const int g = tid / 25;
        const int s = tid - g * 25;
        const int slc = tid / 10;
        const int e0  = 2 * (tid - slc * 10);

        float wreg[6][20];
        if (tid < 250) {
#pragma unroll
            for (int r = 0; r < 6; ++r) {
                const int rl = g * 6 + r;
                const int gate = rl / 20, jl = rl - gate * 20;
                const float* wr = Whh + (size_t)(gate * 500 + j0 + jl) * H + s * 20;
#pragma unroll
                for (int c = 0; c < 5; ++c)
                    *(float4*)&wreg[r][c * 4] = *(const float4*)(wr + c * 4);
            }
        }
        float bb = 0.f;
        if (tid < ROWS) {
            const int gate = tid / 20, jl = tid - gate * 20;
            bb = bhh[gate * 500 + j0 + jl];
        }
        float hown = (tid < HSL) ? h0[j0 + tid] : 0.f;

        if (tid < HSL)
            __hip_atomic_store(hbuf + 800 + wg * 32 + tid,
                               ((unsigned long long)1u << 32) | (unsigned)__float_as_uint(hown),
                               __ATOMIC_RELAXED, __HIP_MEMORY_SCOPE_AGENT);

        for (int t = 0; t < SEQ; ++t) {
            const unsigned want = (unsigned)(t + 1);
            const int rb = (t + 1) & 1;
            float ir = 0.f, iz = 0.f, inn = 0.f;
            if (tid < HSL) {
                const float* gi = Gi + (size_t)t * G3 + j0 + tid;
                ir = gi[0]; iz = gi[500]; inn = gi[1000];
            }
            if (tid < 250) {
                const unsigned long long* pa = hbuf + rb * 800 + slc * 32 + e0;
                unsigned long long v0, v1;
                do {
                    v0 = __hip_atomic_load(pa,     __ATOMIC_RELAXED, __HIP_MEMORY_SCOPE_AGENT);
                    v1 = __hip_atomic_load(pa + 1, __ATOMIC_RELAXED, __HIP_MEMORY_SCOPE_AGENT);
                } while (((unsigned)(v0 >> 32) != want) || ((unsigned)(v1 >> 32) != want));
                h_s[2 * tid]     = __uint_as_float((unsigned)v0);
                h_s[2 * tid + 1] = __uint_as_float((unsigned)v1);
            }
            __syncthreads();
            if (tid < 250) {
                float hv[20];
#pragma unroll
                for (int c = 0; c < 5; ++c)
                    *(float4*)&hv[c * 4] = *(const float4*)&h_s[s * 20 + c * 4];
                float acc[6] = {0.f, 0.f, 0.f, 0.f, 0.f, 0.f};
#pragma unroll
                for (int i = 0; i < 20; ++i)
#pragma unroll
                    for (int r = 0; r < 6; ++r) acc[r] = fmaf(wreg[r][i], hv[i], acc[r]);
#pragma unroll
                for (int r = 0; r < 6; ++r) p_s[(g * 6 + r) * 26 + s] = acc[r];
            }
            __syncthreads();
            if (tid < ROWS) {
                float sum = 0.f;
#pragma unroll 5
                for (int i = 0; i < 25; ++i) sum += p_s[tid * 26 + i];
                gh_s[tid] = sum + bb;
            }
            __syncthreads();
            if (tid < HSL) {
                const int j = j0 + tid;
                const float hr = gh_s[tid], hz = gh_s[HSL + tid], hn = gh_s[2 * HSL + tid];
                const float r = 1.f / (1.f + __expf(-(ir + hr)));
                const float z = 1.f / (1.f + __expf(-(iz + hz)));
                const float n = tanhf(inn + r * hn);
                const float hnew = (1.f - z) * n + z * hown;
                hown = hnew;
                // dechs must be agent-visible: cross-XCD workers read it
                __hip_atomic_store(&dechs[(size_t)t * H + j], hnew,
                                   __ATOMIC_RELAXED, __HIP_MEMORY_SCOPE_AGENT);
                const unsigned long long w =
                    ((unsigned long long)(unsigned)(t + 2) << 32) |
                    (unsigned)__float_as_uint(hnew);
                if ((t & 127) == 127)  // drain dechs to coherence point at 128-row epochs
                    __hip_atomic_store(hbuf + (t & 1) * 800 + wg * 32 + tid, w,
                                       __ATOMIC_RELEASE, __HIP_MEMORY_SCOPE_AGENT);
                else
                    __hip_atomic_store(hbuf + (t & 1) * 800 + wg * 32 + tid, w,
                                       __ATOMIC_RELAXED, __HIP_MEMORY_SCOPE_AGENT);
            }
        }
        return;
    }

    // ================= persistent logits worker =================
    __shared__ __align__(16) float As[LG_BK * LG_BM];
    __shared__ __align__(16) float Bs[LG_BK * LG_BN];
    __shared__ int go;

    for (;;) {
        __syncthreads();
        if (tid == 0) go = atomicAdd(ticket, 1);
        __syncthreads();
        const int tk = go;
        if (tk >= NTILES) return;
        const int by = tk / NT, bx = tk - by * NT;
        const int n0 = bx * LG_BN;
        const int m0 = by * LG_BM;

        // ---- wait until decoder rows [0, m0+128) are published & drained ----
        // release at t=127/255/383/511 (all odd -> buf1); any buf1 tag >= m0+129
        // from a lane implies that lane's dechs stores through row m0+127 are visible.
        const unsigned T_need = (unsigned)(m0 + 129);
        if (tid < 64) {
            for (;;) {
                unsigned mn = 0xFFFFFFFFu;
                for (int i = tid; i < 500; i += 64) {
                    const int sl = i / 20, j = i - sl * 20;
                    unsigned long long w = __hip_atomic_load(
                        hbuf + 800 + sl * 32 + j,
                        __ATOMIC_RELAXED, __HIP_MEMORY_SCOPE_AGENT);
                    unsigned tg = (unsigned)(w >> 32);
                    mn = mn < tg ? mn : tg;
                }
#pragma unroll
                for (int off = 32; off; off >>= 1) {
                    unsigned o = __shfl_xor(mn, off);
                    mn = mn < o ? mn : o;
                }
                if (mn >= T_need) break;
                __builtin_amdgcn_s_sleep(32);   // ~2k cycles backoff: keep LLC lines cool
            }
        }
        __syncthreads();
        __threadfence();                        // acquire: invalidate stale L1/L2 lines

        // ---- 128x128 logits tile with fused sum-exp / argmax partials ----
        const int tx = tid & 15, ty = tid >> 4;
        float acc[8][8] = {};
        for (int k0 = 0; k0 < H; k0 += LG_BK) {
            for (int x = tid; x < 640; x += 256) {      // 128 rows x 5 float4
                int m = x / 5, kq = x - m * 5;
                float4 v = *(const float4*)(dechs + (size_t)(m0 + m) * H + k0 + kq * 4);
                int kb = kq * 4;
                As[(kb + 0) * LG_BM + m] = v.x; As[(kb + 1) * LG_BM + m] = v.y;
                As[(kb + 2) * LG_BM + m] = v.z; As[(kb + 3) * LG_BM + m] = v.w;
            }
            for (int x = tid; x < 640; x += 256) {
                int n = x / 5, kq = x - n * 5;
                int gn = n0 + n;
                float4 v = make_float4(0.f, 0.f, 0.f, 0.f);
                if (gn < V) v = *(const float4*)(outW + (size_t)gn * H + k0 + kq * 4);
                int kb = kq * 4;
                Bs[(kb + 0) * LG_BN + n] = v.x; Bs[(kb + 1) * LG_BN + n] = v.y;
                Bs[(kb + 2) * LG_BN + n] = v.z; Bs[(kb + 3) * LG_BN + n] = v.w;
            }
            __syncthreads();
#pragma unroll 5
            for (int kk = 0; kk < LG_BK; ++kk) {
                float a[8], b[8];
                *(float4*)&a[0] = *(const float4*)&As[kk * LG_BM + ty * 8];
                *(float4*)&a[4] = *(const float4*)&As[kk * LG_BM + ty * 8 + 4];
                *(float4*)&b[0] = *(const float4*)&Bs[kk * LG_BN + tx * 8];
                *(float4*)&b[4] = *(const float4*)&Bs[kk * LG_BN + tx * 8 + 4];
#pragma unroll
                for (int i = 0; i < 8; i++)
#pragma unroll
                    for (int j = 0; j < 8; j++) acc[i][j] = fmaf(a[i], b[j], acc[i][j]);
            }
            __syncthreads();
        }
        float bcol[8]; int gncol[8]; bool bval[8];
#pragma unroll
        for (int j = 0; j < 8; j++) {
            int gn = n0 + tx * 8 + j;
            gncol[j] = gn; bval[j] = gn < V; bcol[j] = bval[j] ? outb[gn] : 0.f;
        }
#pragma unroll
        for (int i = 0; i < 8; i++) {
            int gm = m0 + ty * 8 + i;
            float mx = -3.4e38f; unsigned mi = 0; float se = 0.f;
#pragma unroll
            for (int j = 0; j < 8; j++) {
                if (bval[j]) {
                    float l = acc[i][j] + bcol[j];
                    se += __expf(l);
                    if (l > mx) { mx = l; mi = (unsigned)gncol[j]; }
                }
            }
            unsigned u = __float_as_uint(mx);
            unsigned key = (u & 0x80000000u) ? ~u : (u | 0x80000000u);
            unsigned long long pk = ((unsigned long long)key << 32) |
                                    (unsigned long long)(0xFFFFFFFFu - mi);
#pragma unroll
            for (int off = 1; off < 16; off <<= 1) {
                unsigned long long pk2 = __shfl_xor(pk, off);
                se += __shfl_xor(se, off);
                if (pk2 > pk) pk = pk2;
            }
            if (tx == 0) {
                S_part[(size_t)gm * NT + bx] = se;
                P_part[(size_t)gm * NT + bx] = pk;
            }
        }
    }
}

__global__ __launch_bounds__(128) void k_reduce_rows(
    const float* __restrict__ S_part, const unsigned long long* __restrict__ P_part,
    float* __restrict__ Sfin, float* __restrict__ out_argmax)
{
    const int row = blockIdx.x, tid = threadIdx.x;
    float s = 0.f; unsigned long long p = 0ull;
    for (int i = tid; i < NT; i += 128) {
        s += S_part[(size_t)row * NT + i];
        unsigned long long q = P_part[(size_t)row * NT + i];
        if (q > p) p = q;
    }
#pragma unroll
    for (int off = 1; off < 64; off <<= 1) {
        s += __shfl_xor(s, off);
        unsigned long long q = __shfl_xor(p, off);
        if (q > p) p = q;
    }
    __shared__ float s2[2];
    __shared__ unsigned long long p2[2];
    if ((tid & 63) == 0) { s2[tid >> 6] = s; p2[tid >> 6] = p; }
    __syncthreads();
    if (tid == 0) {
        s = s2[0] + s2[1];
        p = p2[0] > p2[1] ? p2[0] : p2[1];
        Sfin[row] = s;
        unsigned idx = 0xFFFFFFFFu - (unsigned)(p & 0xFFFFFFFFull);
        out_argmax[row] = (float)idx;
    }
}

__global__ __launch_bounds__(64) void k_ltgt(
    const float* __restrict__ A, const float* __restrict__ Bw,
    const float* __restrict__ bias, const int* __restrict__ tgt,
    float* __restrict__ ltgt)
{
    const int row = blockIdx.x, lane = threadIdx.x;
    const int tok = tgt[row];
    const float* a = A + (size_t)row * H;
    const float* b = Bw + (size_t)tok * H;
    float s = 0.f;
    for (int k = lane; k < H; k += 64) s = fmaf(a[k], b[k], s);
#pragma unroll
    for (int off = 1; off < 64; off <<= 1) s += __shfl_xor(s, off);
    if (lane == 0) ltgt[row] = s + bias[tok];
}

__global__ __launch_bounds__(512) void k_final(
    const float* __restrict__ Sfin, const float* __restrict__ ltgt, float* __restrict__ d_out)
{
    __shared__ float red[512];
    const int t = threadIdx.x;
    red[t] = logf(Sfin[t]) - ltgt[t];
    __syncthreads();
    for (int s = 256; s > 0; s >>= 1) {
        if (t < s) red[t] += red[t + s];
        __syncthreads();
    }
    if (t == 0) d_out[0] = red[0];
}

extern "C" void kernel_launch(void* const* d_in, const int* in_sizes, int n_in,
                              void* d_out, int out_size, void* d_ws, size_t ws_size,
                              hipStream_t stream) {
    const int*   enc_ids = (const int*)d_in[0];
    const int*   tgt     = (const int*)d_in[1];
    const float* enc_h0  = (const float*)d_in[2];
    const float* enc_emb = (const float*)d_in[3];
    const float* enc_Wih = (const float*)d_in[4];
    const float* enc_Whh = (const float*)d_in[5];
    const float* enc_bih = (const float*)d_in[6];
    const float* enc_bhh = (const float*)d_in[7];
    const float* dec_emb = (const float*)d_in[8];
    const float* dec_Wih = (const float*)d_in[9];
    const float* dec_Whh = (const float*)d_in[10];
    const float* dec_bih = (const float*)d_in[11];
    const float* dec_bhh = (const float*)d_in[12];
    const float* out_W   = (const float*)d_in[13];
    const float* out_b   = (const float*)d_in[14];
    float* out = (float*)d_out;

    char* ws = (char*)d_ws;
    unsigned long long* hbufE = (unsigned long long*)(ws + OFS_HBUF_E);
    unsigned long long* hbufD = (unsigned long long*)(ws + OFS_HBUF_D);
    float* ench   = (float*)(ws + OFS_ENCH);
    int*   ticket = (int*)(ws + OFS_TICKET);
    float* gi_enc = (float*)(ws + OFS_GI_ENC);
    float* gi_dec = (float*)(ws + OFS_GI_DEC);
    float* dechs  = (float*)(ws + OFS_DECHS);
    float* Spart  = (float*)(ws + OFS_SPART);
    unsigned long long* Ppart = (unsigned long long*)(ws + OFS_PPART);
    float* ltgt   = (float*)(ws + OFS_LTGT);
    float* Sfin   = (float*)(ws + OFS_SFIN);

    k_init<<<dim3(1), dim3(256), 0, stream>>>(hbufE, hbufD, ticket);
    k_gi_gemm<<<dim3(24, 8, 2), dim3(256), 0, stream>>>(
        enc_emb, enc_Wih, enc_bih, enc_ids,
        dec_emb, dec_Wih, dec_bih, tgt, gi_enc, gi_dec);
    k_gru<<<dim3(NB), dim3(256), 0, stream>>>(enc_Whh, enc_bhh, gi_enc, enc_h0,
                                              hbufE, ench, out + 1, SEQ);
    k_dec_fused<<<dim3(NB + NWORK), dim3(256), 0, stream>>>(
        dec_Whh, dec_bhh, gi_dec, ench, hbufD, dechs,
        out_W, out_b, Spart, Ppart, ticket);
    k_ltgt<<<dim3(SEQ), dim3(64), 0, stream>>>(dechs, out_W, out_b, tgt, ltgt);
    k_reduce_rows<<<dim3(SEQ), dim3(128), 0, stream>>>(Spart, Ppart, Sfin, out + 1 + H);
    k_final<<<dim3(1), dim3(512), 0, stream>>>(Sfin, ltgt, out);
}